// Round 4
// baseline (186.280 us; speedup 1.0000x reference)
//
#include <hip/hip_runtime.h>
#include <hip/hip_bf16.h>

#define TPB 256

constexpr int B_    = 262144;
constexpr int WIN_  = 5;
constexpr int VOCAB_= 100000;
constexpr int EMB_  = 50;
constexpr int HID_  = 250;   // real K and hidden width
constexpr int OUT_  = 36;
constexpr int KP    = 256;   // padded K (WIN*EMB and HID padded)
constexpr int NP    = 256;   // padded hidden
constexpr int OP    = 48;    // padded out cols (3 x 16)
constexpr int BM    = 64;    // rows per block

typedef __attribute__((ext_vector_type(8))) short fragA;  // 8 bf16 in 4 VGPRs
typedef __attribute__((ext_vector_type(4))) float fragC;  // 4 f32 acc

__device__ __forceinline__ short f2b(float f) {
    __hip_bfloat16 h = __float2bfloat16(f);      // native RNE cvt
    return *reinterpret_cast<short*>(&h);
}

__device__ __forceinline__ unsigned pack2(float x, float y) {
    return (unsigned)(unsigned short)f2b(x) | ((unsigned)(unsigned short)f2b(y) << 16);
}

__device__ __forceinline__ float fast_tanh(float x) {
    float e = __expf(2.f * x);
    return 1.f - __fdividef(2.f, e + 1.f);
}

// xs tile: 64 rows x 512B, XOR-swizzled. byte_in_row b gets b ^ ((row&7)<<4):
// keeps fragA (16B) reads spread across 8 bank-groups -> effectively conflict-free,
// while the row stride stays 512B (32KB total => exactly 5 blocks/CU).
__device__ __forceinline__ void* xp(char* xs, int row, int b) {
    return xs + (row << 9) + (b ^ ((row & 7) << 4));
}

// Convert W1 -> wT[n][k] bf16 (256x256, zero-padded), W2 -> woT[o][k] bf16 (48x256)
__global__ void prep_weights(const float* __restrict__ w_in,
                             const float* __restrict__ w_out,
                             short* __restrict__ wT,
                             short* __restrict__ woT) {
    int id = blockIdx.x * blockDim.x + threadIdx.x;
    if (id < NP * KP) {
        int n = id >> 8, k = id & 255;
        float v = (n < HID_ && k < HID_) ? w_in[k * HID_ + n] : 0.f;
        wT[id] = f2b(v);
    } else {
        int id2 = id - NP * KP;
        if (id2 < OP * KP) {
            int o = id2 >> 8, k = id2 & 255;
            float v = (o < OUT_ && k < HID_) ? w_out[k * OUT_ + o] : 0.f;
            woT[id2] = f2b(v);
        }
    }
}

__launch_bounds__(TPB, 5)
__global__ void tagger_main(const int* __restrict__ idx,
                            const float* __restrict__ emb,
                            const float* __restrict__ b_in,
                            const float* __restrict__ b_out,
                            const short* __restrict__ wT,
                            const short* __restrict__ woT,
                            float* __restrict__ out) {
    __shared__ char xs[BM * 512];      // x tile, later reused as h tile (32768 B exactly)

    const int tid   = threadIdx.x;
    const int lane  = tid & 63;
    const int wave  = tid >> 6;
    const int l16   = lane & 15;
    const int khalf = lane >> 4;       // 0..3, selects k sub-block of 8
    const int r0    = blockIdx.x * BM;

    // ---- gather: 4 threads per (row,win) pair; 7 independent float2 loads each ----
    {
        const int sub = tid & 3;
        #pragma unroll
        for (int it = 0; it < 5; ++it) {
            int p   = it * 64 + (tid >> 2);       // pair 0..319
            int row = p / 5;                      // magic-mul div
            int win = p - row * 5;
            int iv  = idx[r0 * WIN_ + p];         // L1-cached, 4-way redundant
            bool valid = (iv >= 0 && iv < VOCAB_);
            const float* base = emb + (long long)(valid ? iv : 0) * EMB_;
            #pragma unroll
            for (int j = 0; j < 7; ++j) {
                int c = sub + 4 * j;              // float2 chunk 0..24
                if (c < 25) {
                    float2 v = make_float2(0.f, 0.f);
                    if (valid) v = *(const float2*)(base + 2 * c);
                    *(unsigned*)xp(xs, row, 100 * win + 4 * c) = pack2(v.x, v.y);
                }
            }
        }
        // zero-fill pad columns 250..255 (K padding): MFMA sums all 256 k's;
        // uninitialized LDS can be NaN and NaN*0 poisons the whole row (R2 bug)
        if (tid < 192) {
            int row = tid / 3, c = tid - row * 3;
            *(unsigned*)xp(xs, row, 500 + 4 * c) = 0u;
        }
    }
    __syncthreads();

    // ---- layer 1: [64 x 256] x [256 x 256]; wave owns 64 rows x 64 cols.
    //      B-fragments loaded JIT from global (L2-resident wT) -> no barriers, no LDS staging.
    fragC acc[4][4];
    #pragma unroll
    for (int mf = 0; mf < 4; ++mf)
        #pragma unroll
        for (int nf = 0; nf < 4; ++nf)
            acc[mf][nf] = (fragC){0.f, 0.f, 0.f, 0.f};

    const int nb = wave * 64;

    #pragma unroll 2
    for (int kk = 0; kk < 8; ++kk) {
        fragA a[4], b[4];
        #pragma unroll
        for (int mf = 0; mf < 4; ++mf)
            a[mf] = *(const fragA*)xp(xs, mf * 16 + l16, 64 * kk + 16 * khalf);
        #pragma unroll
        for (int nf = 0; nf < 4; ++nf)
            b[nf] = *(const fragA*)&wT[(nb + nf * 16 + l16) * KP + kk * 32 + khalf * 8];
        #pragma unroll
        for (int mf = 0; mf < 4; ++mf)
            #pragma unroll
            for (int nf = 0; nf < 4; ++nf)
                acc[mf][nf] = __builtin_amdgcn_mfma_f32_16x16x32_bf16(a[mf], b[nf], acc[mf][nf], 0, 0, 0);
    }

    __syncthreads();  // all xs (x) reads complete before overwriting with h

    // ---- epilogue 1: bias + tanh -> h (bf16) back into xs ----
    #pragma unroll
    for (int nf = 0; nf < 4; ++nf) {
        int col = nb + nf * 16 + l16;
        float bi = (col < HID_) ? b_in[col] : 0.f;
        #pragma unroll
        for (int mf = 0; mf < 4; ++mf) {
            #pragma unroll
            for (int j = 0; j < 4; ++j) {
                int row = mf * 16 + khalf * 4 + j;
                float h = fast_tanh(acc[mf][nf][j] + bi);
                *(short*)xp(xs, row, 2 * col) = f2b(h);
            }
        }
    }
    __syncthreads();

    // ---- layer 2: [64 x 256] x [256 x 48]; each wave owns 16 rows x 48 cols ----
    fragC acc2[3];
    #pragma unroll
    for (int of = 0; of < 3; ++of) acc2[of] = (fragC){0.f, 0.f, 0.f, 0.f};

    #pragma unroll 2
    for (int kk = 0; kk < 8; ++kk) {
        fragA ha = *(const fragA*)xp(xs, wave * 16 + l16, 64 * kk + 16 * khalf);
        #pragma unroll
        for (int of = 0; of < 3; ++of) {
            fragA wb = *(const fragA*)&woT[(of * 16 + l16) * KP + kk * 32 + khalf * 8];
            acc2[of] = __builtin_amdgcn_mfma_f32_16x16x32_bf16(ha, wb, acc2[of], 0, 0, 0);
        }
    }

    // ---- epilogue 2: bias + store f32 ----
    #pragma unroll
    for (int of = 0; of < 3; ++of) {
        int o = of * 16 + l16;
        if (o < OUT_) {
            float bo = b_out[o];
            #pragma unroll
            for (int j = 0; j < 4; ++j) {
                int row = r0 + wave * 16 + khalf * 4 + j;
                out[row * OUT_ + o] = acc2[of][j] + bo;
            }
        }
    }
}

extern "C" void kernel_launch(void* const* d_in, const int* in_sizes, int n_in,
                              void* d_out, int out_size, void* d_ws, size_t ws_size,
                              hipStream_t stream) {
    const int*   idx   = (const int*)d_in[0];
    const float* emb   = (const float*)d_in[1];
    const float* w_in  = (const float*)d_in[2];
    const float* b_in  = (const float*)d_in[3];
    const float* w_out = (const float*)d_in[4];
    const float* b_out = (const float*)d_in[5];
    float* out = (float*)d_out;

    short* wT  = (short*)d_ws;          // 256*256 bf16 = 128 KiB
    short* woT = wT + NP * KP;          // 48*256  bf16 =  24 KiB

    int prep_threads = NP * KP + OP * KP;  // 77824 = 304 * 256
    prep_weights<<<(prep_threads + TPB - 1) / TPB, TPB, 0, stream>>>(w_in, w_out, wT, woT);
    tagger_main<<<B_ / BM, TPB, 0, stream>>>(idx, emb, b_in, b_out, wT, woT, out);
}

// Round 5
// 149.603 us; speedup vs baseline: 1.2452x; 1.2452x over previous
//
#include <hip/hip_runtime.h>
#include <hip/hip_bf16.h>

#define TPB 256

constexpr int B_    = 262144;
constexpr int WIN_  = 5;
constexpr int VOCAB_= 100000;
constexpr int EMB_  = 50;
constexpr int HID_  = 250;
constexpr int OUT_  = 36;
constexpr int KP    = 256;   // padded K for layer 2 (HID 250 -> 256)
constexpr int NP    = 256;   // padded hidden
constexpr int OP    = 48;    // padded out cols (3 x 16)
constexpr int BM    = 64;    // rows per block
constexpr int K1    = 320;   // layer-1 K: 5 windows x 64 (each 50 padded to 64)
constexpr int ROWB  = 640;   // xs row bytes = K1 * 2

typedef __attribute__((ext_vector_type(8))) short fragA;  // 8 bf16
typedef __attribute__((ext_vector_type(4))) float fragC;  // 4 f32 acc

__device__ __forceinline__ short f2b(float f) {
    __hip_bfloat16 h = __float2bfloat16(f);      // native RNE cvt
    return *reinterpret_cast<short*>(&h);
}

__device__ __forceinline__ unsigned pack2(float x, float y) {
    return (unsigned)(unsigned short)f2b(x) | ((unsigned)(unsigned short)f2b(y) << 16);
}

__device__ __forceinline__ float fast_tanh(float x) {
    float e = __expf(2.f * x);
    return 1.f - __fdividef(2.f, e + 1.f);
}

// xs tile: 64 rows x 640B. Row stride 640B == 0 mod 128 -> all rows hit the same
// banks; XOR-swizzle byte ^ ((row&7)<<4) spreads 8 consecutive rows across the
// full 128B bank cycle -> 2-way (free) on fragA reads and b128 gather writes.
__device__ __forceinline__ void* xp(char* xs, int row, int b) {
    return xs + row * ROWB + (b ^ ((row & 7) << 4));
}

// emb_table f32 [VOCAB][50] -> bf16 [VOCAB][64], cols 50..63 zero (row = 128B aligned)
__global__ void prep_emb(const float* __restrict__ emb, short* __restrict__ emb_b) {
    int id = blockIdx.x * TPB + threadIdx.x;           // one dword (2 cols) each
    if (id >= VOCAB_ * 32) return;
    int row = id >> 5, c2 = id & 31;
    unsigned v = 0u;
    if (c2 < 25) {
        float2 f = *(const float2*)(emb + row * EMB_ + 2 * c2);  // 8B-aligned
        v = pack2(f.x, f.y);
    }
    ((unsigned*)emb_b)[id] = v;
}

// W1 -> wT[n][k1] bf16 (256x320, window-padded, zero elsewhere), W2 -> woT[o][k] (48x256)
__global__ void prep_weights(const float* __restrict__ w_in,
                             const float* __restrict__ w_out,
                             short* __restrict__ wT,
                             short* __restrict__ woT) {
    int id = blockIdx.x * TPB + threadIdx.x;
    if (id < NP * K1) {
        int n = id / K1, kp = id - n * K1;
        int w = kp >> 6, e = kp & 63;                  // window, elem-in-window
        float v = (n < HID_ && e < EMB_) ? w_in[(w * EMB_ + e) * HID_ + n] : 0.f;
        wT[id] = f2b(v);
    } else {
        int id2 = id - NP * K1;
        if (id2 < OP * KP) {
            int o = id2 >> 8, k = id2 & 255;
            float v = (o < OUT_ && k < HID_) ? w_out[k * OUT_ + o] : 0.f;
            woT[id2] = f2b(v);
        }
    }
}

template<bool BF>
__launch_bounds__(TPB, 4)
__global__ void tagger_main(const int* __restrict__ idx,
                            const float* __restrict__ emb,
                            const short* __restrict__ emb_b,
                            const float* __restrict__ b_in,
                            const float* __restrict__ b_out,
                            const short* __restrict__ wT,
                            const short* __restrict__ woT,
                            float* __restrict__ out) {
    __shared__ char xs[BM * ROWB];     // 40960 B -> 4 blocks/CU

    const int tid   = threadIdx.x;
    const int lane  = tid & 63;
    const int wave  = tid >> 6;
    const int l16   = lane & 15;
    const int khalf = lane >> 4;
    const int r0    = blockIdx.x * BM;

    // ---- gather into xs [64][5*128B] ----
    if constexpr (BF) {
        // bf16 table: 8 threads per (row,win), one 16B chunk each; pad cols come
        // zeroed from the table itself -> every byte of xs written, no NaN trap.
        #pragma unroll
        for (int it = 0; it < 10; ++it) {
            int c   = it * TPB + tid;          // chunk 0..2559
            int p   = c >> 3, sub = c & 7;     // pair 0..319, 16B chunk 0..7
            int row = p / 5, win = p - row * 5;
            int iv  = idx[r0 * WIN_ + p];
            fragA v = {0, 0, 0, 0, 0, 0, 0, 0};
            if (iv >= 0 && iv < VOCAB_)
                v = *(const fragA*)(emb_b + iv * 64 + sub * 8);   // 16B aligned
            *(fragA*)xp(xs, row, win * 128 + sub * 16) = v;
        }
    } else {
        // f32 fallback (small d_ws): 4 threads per (row,win), float2 chunks
        const int sub = tid & 3;
        #pragma unroll
        for (int it = 0; it < 5; ++it) {
            int p   = it * 64 + (tid >> 2);
            int row = p / 5, win = p - row * 5;
            int iv  = idx[r0 * WIN_ + p];
            bool valid = (iv >= 0 && iv < VOCAB_);
            const float* base = emb + (valid ? iv : 0) * EMB_;
            #pragma unroll
            for (int j = 0; j < 7; ++j) {
                int ch = sub + 4 * j;
                if (ch < 25) {
                    float2 v = make_float2(0.f, 0.f);
                    if (valid) v = *(const float2*)(base + 2 * ch);
                    *(unsigned*)xp(xs, row, win * 128 + 4 * ch) = pack2(v.x, v.y);
                }
            }
            for (int ch = 25 + sub; ch < 32; ch += 4)   // zero pad cols 50..63
                *(unsigned*)xp(xs, row, win * 128 + 4 * ch) = 0u;
        }
    }
    __syncthreads();

    // ---- layer 1: [64 x 320] x [320 x 256]; wave owns 64 rows x 64 cols.
    //      B-fragments JIT from global (L2-resident wT) -> no barriers.
    fragC acc[4][4];
    #pragma unroll
    for (int mf = 0; mf < 4; ++mf)
        #pragma unroll
        for (int nf = 0; nf < 4; ++nf)
            acc[mf][nf] = (fragC){0.f, 0.f, 0.f, 0.f};

    const int nb = wave * 64;

    #pragma unroll 2
    for (int kk = 0; kk < 10; ++kk) {
        fragA a[4], b[4];
        #pragma unroll
        for (int mf = 0; mf < 4; ++mf)
            a[mf] = *(const fragA*)xp(xs, mf * 16 + l16, kk * 64 + khalf * 16);
        #pragma unroll
        for (int nf = 0; nf < 4; ++nf)
            b[nf] = *(const fragA*)&wT[(nb + nf * 16 + l16) * K1 + kk * 32 + khalf * 8];
        #pragma unroll
        for (int mf = 0; mf < 4; ++mf)
            #pragma unroll
            for (int nf = 0; nf < 4; ++nf)
                acc[mf][nf] = __builtin_amdgcn_mfma_f32_16x16x32_bf16(a[mf], b[nf], acc[mf][nf], 0, 0, 0);
    }

    __syncthreads();  // all xs (x) reads complete before overwriting with h

    // ---- epilogue 1: bias + tanh -> h (bf16) back into xs cols 0..255 ----
    #pragma unroll
    for (int nf = 0; nf < 4; ++nf) {
        int col = nb + nf * 16 + l16;
        float bi = (col < HID_) ? b_in[col] : 0.f;
        #pragma unroll
        for (int mf = 0; mf < 4; ++mf) {
            #pragma unroll
            for (int j = 0; j < 4; ++j) {
                int row = mf * 16 + khalf * 4 + j;
                float h = fast_tanh(acc[mf][nf][j] + bi);
                *(short*)xp(xs, row, 2 * col) = f2b(h);
            }
        }
    }
    __syncthreads();

    // ---- layer 2: [64 x 256] x [256 x 48]; each wave owns 16 rows x 48 cols ----
    fragC acc2[3];
    #pragma unroll
    for (int of = 0; of < 3; ++of) acc2[of] = (fragC){0.f, 0.f, 0.f, 0.f};

    #pragma unroll 2
    for (int kk = 0; kk < 8; ++kk) {
        fragA ha = *(const fragA*)xp(xs, wave * 16 + l16, 64 * kk + 16 * khalf);
        #pragma unroll
        for (int of = 0; of < 3; ++of) {
            fragA wb = *(const fragA*)&woT[(of * 16 + l16) * KP + kk * 32 + khalf * 8];
            acc2[of] = __builtin_amdgcn_mfma_f32_16x16x32_bf16(ha, wb, acc2[of], 0, 0, 0);
        }
    }

    // ---- epilogue 2: bias + store f32 ----
    #pragma unroll
    for (int of = 0; of < 3; ++of) {
        int o = of * 16 + l16;
        if (o < OUT_) {
            float bo = b_out[o];
            #pragma unroll
            for (int j = 0; j < 4; ++j) {
                int row = r0 + wave * 16 + khalf * 4 + j;
                out[row * OUT_ + o] = acc2[of][j] + bo;
            }
        }
    }
}

extern "C" void kernel_launch(void* const* d_in, const int* in_sizes, int n_in,
                              void* d_out, int out_size, void* d_ws, size_t ws_size,
                              hipStream_t stream) {
    const int*   idx   = (const int*)d_in[0];
    const float* emb   = (const float*)d_in[1];
    const float* w_in  = (const float*)d_in[2];
    const float* b_in  = (const float*)d_in[3];
    const float* w_out = (const float*)d_in[4];
    const float* b_out = (const float*)d_in[5];
    float* out = (float*)d_out;

    const size_t emb_b_elems = (size_t)VOCAB_ * 64;                 // 12.8 MB
    const size_t need_bf = (emb_b_elems + NP * K1 + OP * KP) * 2;
    const bool bf = (ws_size >= need_bf);

    short* emb_b = nullptr;
    short* wT;
    if (bf) {
        emb_b = (short*)d_ws;
        wT    = emb_b + emb_b_elems;
        prep_emb<<<VOCAB_ * 32 / TPB, TPB, 0, stream>>>(emb, emb_b);  // 12500 blocks
    } else {
        wT = (short*)d_ws;
    }
    short* woT = wT + NP * K1;

    int prep_threads = NP * K1 + OP * KP;  // 94208
    prep_weights<<<(prep_threads + TPB - 1) / TPB, TPB, 0, stream>>>(w_in, w_out, wT, woT);

    if (bf)
        tagger_main<true><<<B_ / BM, TPB, 0, stream>>>(idx, emb, emb_b, b_in, b_out, wT, woT, out);
    else
        tagger_main<false><<<B_ / BM, TPB, 0, stream>>>(idx, emb, emb_b, b_in, b_out, wT, woT, out);
}

// Round 6
// 148.614 us; speedup vs baseline: 1.2535x; 1.0067x over previous
//
#include <hip/hip_runtime.h>
#include <hip/hip_bf16.h>

#define TPB 256

constexpr int B_    = 262144;
constexpr int WIN_  = 5;
constexpr int VOCAB_= 100000;
constexpr int EMB_  = 50;
constexpr int HID_  = 250;
constexpr int OUT_  = 36;
constexpr int KP    = 256;   // padded K for layer 2 (HID 250 -> 256)
constexpr int NP    = 256;   // padded hidden
constexpr int OP    = 48;    // padded out cols (3 x 16)
constexpr int BM    = 64;    // rows per block
constexpr int K1    = 320;   // layer-1 K: 5 windows x 64 (each 50 padded to 64)
constexpr int ROWB  = 640;   // xs row bytes = K1 * 2

typedef __attribute__((ext_vector_type(8))) short fragA;  // 8 bf16
typedef __attribute__((ext_vector_type(4))) float fragC;  // 4 f32 acc

__device__ __forceinline__ short f2b(float f) {
    __hip_bfloat16 h = __float2bfloat16(f);      // native RNE cvt
    return *reinterpret_cast<short*>(&h);
}

__device__ __forceinline__ unsigned pack2(float x, float y) {
    return (unsigned)(unsigned short)f2b(x) | ((unsigned)(unsigned short)f2b(y) << 16);
}

__device__ __forceinline__ float fast_tanh(float x) {
    float e = __expf(2.f * x);
    return 1.f - __fdividef(2.f, e + 1.f);
}

// xs tile: 64 rows x 640B. Row stride 640 % 128 == 0 -> all rows alias the same
// bank cycle; XOR-swizzle byte ^ ((row&7)<<4) spreads 8 consecutive rows across
// the 128B bank cycle -> conflict-free fragA reads / b128 writes (R5: 0 conflicts).
__device__ __forceinline__ void* xp(char* xs, int row, int b) {
    return xs + row * ROWB + (b ^ ((row & 7) << 4));
}

// emb_table f32 [VOCAB][50] -> bf16 [VOCAB][64], cols 50..63 zero (row = 128B aligned)
__global__ void prep_emb(const float* __restrict__ emb, short* __restrict__ emb_b) {
    int id = blockIdx.x * TPB + threadIdx.x;           // one dword (2 cols) each
    if (id >= VOCAB_ * 32) return;
    int row = id >> 5, c2 = id & 31;
    unsigned v = 0u;
    if (c2 < 25) {
        float2 f = *(const float2*)(emb + row * EMB_ + 2 * c2);  // 8B-aligned
        v = pack2(f.x, f.y);
    }
    ((unsigned*)emb_b)[id] = v;
}

// W1 -> wT[n][k1] bf16 (256x320 window-padded), W2 -> woT[o][k] (48x256),
// b_in -> f32[256] zero-padded, b_out -> f32[48] zero-padded
__global__ void prep_weights(const float* __restrict__ w_in,
                             const float* __restrict__ w_out,
                             const float* __restrict__ b_in,
                             const float* __restrict__ b_out,
                             short* __restrict__ wT,
                             short* __restrict__ woT,
                             float* __restrict__ b_in_p,
                             float* __restrict__ b_out_p) {
    int id = blockIdx.x * TPB + threadIdx.x;
    if (id < NP * K1) {
        int n = id / K1, kp = id - n * K1;
        int w = kp >> 6, e = kp & 63;                  // window, elem-in-window
        float v = (n < HID_ && e < EMB_) ? w_in[(w * EMB_ + e) * HID_ + n] : 0.f;
        wT[id] = f2b(v);
        return;
    }
    int id2 = id - NP * K1;
    if (id2 < OP * KP) {
        int o = id2 >> 8, k = id2 & 255;
        float v = (o < OUT_ && k < HID_) ? w_out[k * OUT_ + o] : 0.f;
        woT[id2] = f2b(v);
        return;
    }
    int id3 = id2 - OP * KP;
    if (id3 < NP) { b_in_p[id3] = (id3 < HID_) ? b_in[id3] : 0.f; return; }
    int id4 = id3 - NP;
    if (id4 < OP) { b_out_p[id4] = (id4 < OUT_) ? b_out[id4] : 0.f; }
}

template<bool BF>
__launch_bounds__(TPB, 4)
__global__ void tagger_main(const int* __restrict__ idx,
                            const float* __restrict__ emb,
                            const short* __restrict__ emb_b,
                            const float* __restrict__ b_in_p,
                            const float* __restrict__ b_out_p,
                            const short* __restrict__ wT,
                            const short* __restrict__ woT,
                            float* __restrict__ out) {
    __shared__ char xs[BM * ROWB];     // 40960 B -> 4 blocks/CU

    const int tid   = threadIdx.x;
    const int lane  = tid & 63;
    const int wave  = tid >> 6;
    const int l16   = lane & 15;
    const int khalf = lane >> 4;
    const int r0    = blockIdx.x * BM;

    // ---- gather into xs [64][5*128B] ----
    if constexpr (BF) {
        #pragma unroll
        for (int it = 0; it < 10; ++it) {
            int c   = it * TPB + tid;          // chunk 0..2559
            int p   = c >> 3, sub = c & 7;     // (row,win) pair, 16B chunk
            int row = p / 5, win = p - row * 5;
            int iv  = idx[r0 * WIN_ + p];
            fragA v = {0, 0, 0, 0, 0, 0, 0, 0};
            if (iv >= 0 && iv < VOCAB_)
                v = *(const fragA*)(emb_b + iv * 64 + sub * 8);   // 16B aligned
            *(fragA*)xp(xs, row, win * 128 + sub * 16) = v;
        }
    } else {
        const int sub = tid & 3;
        #pragma unroll
        for (int it = 0; it < 5; ++it) {
            int p   = it * 64 + (tid >> 2);
            int row = p / 5, win = p - row * 5;
            int iv  = idx[r0 * WIN_ + p];
            bool valid = (iv >= 0 && iv < VOCAB_);
            const float* base = emb + (valid ? iv : 0) * EMB_;
            #pragma unroll
            for (int j = 0; j < 7; ++j) {
                int ch = sub + 4 * j;
                if (ch < 25) {
                    float2 v = make_float2(0.f, 0.f);
                    if (valid) v = *(const float2*)(base + 2 * ch);
                    *(unsigned*)xp(xs, row, win * 128 + 4 * ch) = pack2(v.x, v.y);
                }
            }
            for (int ch = 25 + sub; ch < 32; ch += 4)   // zero pad cols 50..63
                *(unsigned*)xp(xs, row, win * 128 + 4 * ch) = 0u;
        }
    }
    __syncthreads();

    // ---- layer 1: swapped operands -> D[n][batch]: col(lane&15)=batch row,
    //      reg axis = 4 consecutive n. Explicit 1-step prefetch of wT fragments.
    fragC acc[4][4];
    #pragma unroll
    for (int mf = 0; mf < 4; ++mf)
        #pragma unroll
        for (int nf = 0; nf < 4; ++nf)
            acc[mf][nf] = (fragC){0.f, 0.f, 0.f, 0.f};

    const int nb    = wave * 64;
    const int bbase = (nb + l16) * K1 + khalf * 8;   // wT frag base (lane row = n)

    fragA bcur[4];
    #pragma unroll
    for (int nf = 0; nf < 4; ++nf)
        bcur[nf] = *(const fragA*)&wT[bbase + nf * 16 * K1];

    #pragma unroll 2
    for (int kk = 0; kk < 10; ++kk) {
        fragA a[4], bnxt[4];
        #pragma unroll
        for (int mf = 0; mf < 4; ++mf)
            a[mf] = *(const fragA*)xp(xs, mf * 16 + l16, kk * 64 + khalf * 16);
        if (kk < 9) {
            #pragma unroll
            for (int nf = 0; nf < 4; ++nf)
                bnxt[nf] = *(const fragA*)&wT[bbase + nf * 16 * K1 + (kk + 1) * 32];
        }
        #pragma unroll
        for (int mf = 0; mf < 4; ++mf)
            #pragma unroll
            for (int nf = 0; nf < 4; ++nf)
                acc[mf][nf] = __builtin_amdgcn_mfma_f32_16x16x32_bf16(bcur[nf], a[mf], acc[mf][nf], 0, 0, 0);
        if (kk < 9) {
            #pragma unroll
            for (int nf = 0; nf < 4; ++nf) bcur[nf] = bnxt[nf];
        }
    }

    __syncthreads();  // all xs (x) reads complete before overwriting with h

    // ---- epilogue 1: thread owns batch row (mf*16+l16), 4 consecutive n ----
    #pragma unroll
    for (int nf = 0; nf < 4; ++nf) {
        const int n0 = nb + nf * 16 + khalf * 4;
        const float4 bi = *(const float4*)&b_in_p[n0];
        #pragma unroll
        for (int mf = 0; mf < 4; ++mf) {
            const int row = mf * 16 + l16;
            uint2 v;
            v.x = pack2(fast_tanh(acc[mf][nf][0] + bi.x), fast_tanh(acc[mf][nf][1] + bi.y));
            v.y = pack2(fast_tanh(acc[mf][nf][2] + bi.z), fast_tanh(acc[mf][nf][3] + bi.w));
            *(uint2*)xp(xs, row, 2 * n0) = v;   // 8B write, swizzle keeps 8B align
        }
    }
    __syncthreads();

    // ---- layer 2: swapped; wave owns 16 rows x 48 cols ----
    fragC acc2[3];
    #pragma unroll
    for (int of = 0; of < 3; ++of) acc2[of] = (fragC){0.f, 0.f, 0.f, 0.f};

    #pragma unroll 2
    for (int kk = 0; kk < 8; ++kk) {
        fragA ha = *(const fragA*)xp(xs, wave * 16 + l16, 64 * kk + 16 * khalf);
        #pragma unroll
        for (int of = 0; of < 3; ++of) {
            fragA wb = *(const fragA*)&woT[(of * 16 + l16) * KP + kk * 32 + khalf * 8];
            acc2[of] = __builtin_amdgcn_mfma_f32_16x16x32_bf16(wb, ha, acc2[of], 0, 0, 0);
        }
    }

    // ---- epilogue 2: thread owns row (wave*16+l16), 4 consecutive o -> float4 ----
    {
        const int row = r0 + wave * 16 + l16;
        #pragma unroll
        for (int of = 0; of < 3; ++of) {
            const int o0 = of * 16 + khalf * 4;
            if (o0 < OUT_) {
                const float4 bo = *(const float4*)&b_out_p[o0];
                float4 v;
                v.x = acc2[of][0] + bo.x;
                v.y = acc2[of][1] + bo.y;
                v.z = acc2[of][2] + bo.z;
                v.w = acc2[of][3] + bo.w;
                *(float4*)&out[row * OUT_ + o0] = v;   // 16B aligned: 144*row + 4*o0
            }
        }
    }
}

extern "C" void kernel_launch(void* const* d_in, const int* in_sizes, int n_in,
                              void* d_out, int out_size, void* d_ws, size_t ws_size,
                              hipStream_t stream) {
    const int*   idx   = (const int*)d_in[0];
    const float* emb   = (const float*)d_in[1];
    const float* w_in  = (const float*)d_in[2];
    const float* b_in  = (const float*)d_in[3];
    const float* w_out = (const float*)d_in[4];
    const float* b_out = (const float*)d_in[5];
    float* out = (float*)d_out;

    const size_t emb_b_elems = (size_t)VOCAB_ * 64;                 // 12.8 MB
    const size_t tail_elems  = (size_t)NP * K1 + OP * KP + 2 * (NP + OP);  // shorts-equiv
    const size_t need_bf = (emb_b_elems + tail_elems + 256) * 2;
    const bool bf = (ws_size >= need_bf);

    short* emb_b = nullptr;
    short* wT;
    if (bf) {
        emb_b = (short*)d_ws;
        wT    = emb_b + emb_b_elems;
        prep_emb<<<VOCAB_ * 32 / TPB, TPB, 0, stream>>>(emb, emb_b);  // 12500 blocks
    } else {
        wT = (short*)d_ws;
    }
    short* woT = wT + NP * K1;
    float* b_in_p  = (float*)(woT + OP * KP);
    float* b_out_p = b_in_p + NP;

    int prep_threads = NP * K1 + OP * KP + NP + OP;
    prep_weights<<<(prep_threads + TPB - 1) / TPB, TPB, 0, stream>>>(
        w_in, w_out, b_in, b_out, wT, woT, b_in_p, b_out_p);

    if (bf)
        tagger_main<true><<<B_ / BM, TPB, 0, stream>>>(idx, emb, emb_b, b_in_p, b_out_p, wT, woT, out);
    else
        tagger_main<false><<<B_ / BM, TPB, 0, stream>>>(idx, emb, emb_b, b_in_p, b_out_p, wT, woT, out);
}